// Round 1
// baseline (1533.288 us; speedup 1.0000x reference)
//
#include <hip/hip_runtime.h>
#include <hip/hip_bf16.h>
#include <stdint.h>

// Problem constants (QuantizedLinear: B=4,S=2048,D_IN=4096,D_OUT=11008)
#define M_DIM 8192
#define N_DIM 11008
#define K_DIM 4096
#define BM 256
#define BN 256
#define BK 32
#define NT (K_DIM / BK)    // 128 K-steps
#define NBX (N_DIM / BN)   // 43
#define NBY (M_DIM / BM)   // 32
#define NBLK (NBX * NBY)   // 1376 = 8 * 172
#define CPX (NBLK / 8)     // 172 blocks per XCD chunk

typedef __bf16 bf16_8 __attribute__((ext_vector_type(8)));
typedef float f32x4 __attribute__((ext_vector_type(4)));

// ---------------- fp32 -> bf16 (RNE) conversion, 4 elems/thread, fully coalesced ----------------
__device__ __forceinline__ uint32_t pack_bf2(float lo, float hi) {
    uint32_t ulo = __float_as_uint(lo);
    uint32_t uhi = __float_as_uint(hi);
    ulo = (ulo + 0x7fffu + ((ulo >> 16) & 1u)) >> 16;
    uhi = (uhi + 0x7fffu + ((uhi >> 16) & 1u)) >> 16;
    return ulo | (uhi << 16);
}

__global__ __launch_bounds__(256) void cvt_f32_bf16(const float* __restrict__ src,
                                                    uint2* __restrict__ dst, int n4) {
    int i = blockIdx.x * 256 + threadIdx.x;
    if (i >= n4) return;
    float4 a = ((const float4*)src)[i];
    uint2 o;
    o.x = pack_bf2(a.x, a.y);
    o.y = pack_bf2(a.z, a.w);
    dst[i] = o;
}

// ---------------- async global->LDS, 16B per lane ----------------
__device__ __forceinline__ void load_lds16(const __bf16* g, __bf16* l) {
    __builtin_amdgcn_global_load_lds(
        (__attribute__((address_space(1))) void*)(g),
        (__attribute__((address_space(3))) void*)(l),
        16, 0, 0);
}

#define VMCNT(n) asm volatile("s_waitcnt vmcnt(" #n ")" ::: "memory")
#define CFENCE asm volatile("" ::: "memory")

__device__ __forceinline__ void wg_barrier() {
    CFENCE;
    __builtin_amdgcn_s_barrier();
    CFENCE;
}

// Stage one 256x32 A-tile + 256x32 W-tile k-slice into ring slot.
// Per wave: rows [wave*16, +16) of each 128-row half; lane l -> (row l>>2, k-chunk
// (l&3)^((l>>3)&3)). LDS dest stays lane-linear (global_load_lds requirement);
// the XOR swizzle is applied on the SOURCE address (slot c of LDS row r holds
// global k-chunk c ^ ((r&15)>>1 & 3)) -> conflict-free ds_read_b128 later.
__device__ __forceinline__ void stage_tile(const __bf16* Ag, const __bf16* Wg,
                                           __bf16* Asl, __bf16* Bsl,
                                           int wave, long ko) {
    __bf16* la = Asl + wave * 16 * BK;
    __bf16* lb = Bsl + wave * 16 * BK;
    load_lds16(Ag + ko, la);                                   // A rows 0..127 half
    load_lds16(Ag + 128 * (long)K_DIM + ko, la + 128 * BK);    // A rows 128..255 half
    load_lds16(Wg + ko, lb);
    load_lds16(Wg + 128 * (long)K_DIM + ko, lb + 128 * BK);
}

// One K-step of MFMAs: 8 A-frags x 4 B-frags, 16x16x32 bf16.
__device__ __forceinline__ void compute_step(const __bf16* __restrict__ Abase,
                                             const __bf16* __restrict__ Bbase,
                                             f32x4 (&acc)[8][4]) {
    bf16_8 af[8], bv[4];
#pragma unroll
    for (int i = 0; i < 8; i++) af[i] = *(const bf16_8*)(Abase + i * 16 * BK);
#pragma unroll
    for (int j = 0; j < 4; j++) bv[j] = *(const bf16_8*)(Bbase + j * 16 * BK);
    __builtin_amdgcn_s_setprio(1);
#pragma unroll
    for (int i = 0; i < 8; i++)
#pragma unroll
        for (int j = 0; j < 4; j++)
            acc[i][j] = __builtin_amdgcn_mfma_f32_16x16x32_bf16(af[i], bv[j], acc[i][j], 0, 0, 0);
    __builtin_amdgcn_s_setprio(0);
}

// ---------------- GEMM: C[m][n] = (A[m][:] . W[n][:]) * scale[n] + bias[n] ----------------
// 256x256 tile, BK=32, 8 waves (2m x 4n), 4-deep LDS ring (128 KiB), counted vmcnt(8)
// pipeline (stage t+3 while computing t), one raw s_barrier per K-step.
__global__ __launch_bounds__(512, 2) void gemm_bt_scaled(
    const __bf16* __restrict__ A, const __bf16* __restrict__ W,
    const float* __restrict__ scale, const float* __restrict__ bias,
    float* __restrict__ C) {
    __shared__ __align__(16) __bf16 As[4][BM * BK];   // 4 x 16 KiB
    __shared__ __align__(16) __bf16 Bs[4][BN * BK];   // 4 x 16 KiB

    const int t = threadIdx.x;
    const int wave = t >> 6;
    const int lane = t & 63;
    const int wm = wave >> 2;   // 0..1 : wave row (128 rows each)
    const int wn = wave & 3;    // 0..3 : wave col (64 cols each)

    // XCD-aware bijective swizzle: 1376 blocks -> 172-block contiguous chunk per XCD.
    const int bid = (int)blockIdx.x;
    const int swz = (bid & 7) * CPX + (bid >> 3);
    const int by = swz / NBX;
    const int bx = swz - by * NBX;
    const int m0 = by * BM;
    const int n0 = bx * BN;

    // staging source addressing (k-chunk XOR pre-swizzle on global address)
    const int srow = lane >> 2;                            // 0..15
    const int sch = ((lane & 3) ^ ((lane >> 3) & 3)) * 8;  // swizzled k-chunk, elems
    const __bf16* Ag = A + (long)(m0 + wave * 16 + srow) * K_DIM + sch;
    const __bf16* Wg = W + (long)(n0 + wave * 16 + srow) * K_DIM + sch;

    // fragment read addressing (inverse swizzle on the ds_read side)
    const int lrow = lane & 15;
    const int swzr = (lrow >> 1) & 3;
    const int lk = ((lane >> 4) ^ swzr) * 8;
    const int aoff = (wm * 128 + lrow) * BK + lk;
    const int boff = (wn * 64 + lrow) * BK + lk;

    f32x4 acc[8][4] = {};

    // Prologue: stage tiles 0,1,2 (12 loads). vmcnt(8) -> tile 0 landed, 1&2 in flight.
    stage_tile(Ag, Wg, &As[0][0], &Bs[0][0], wave, 0);
    stage_tile(Ag, Wg, &As[1][0], &Bs[1][0], wave, (long)BK);
    stage_tile(Ag, Wg, &As[2][0], &Bs[2][0], wave, 2L * BK);
    VMCNT(8);
    wg_barrier();

    // Main loop: compute tile tt from ring[tt&3]; stage tile tt+3 into ring[(tt+3)&3]
    // (that slot's readers of tile tt-1 finished before the PREVIOUS barrier -> safe).
    // vmcnt(8) at the bottom retires tile tt+1 before the next iteration reads it.
    int tt = 0;
    for (; tt < NT - 3; ++tt) {
        const int sl = tt & 3;
        const int sn = (tt + 3) & 3;
        stage_tile(Ag, Wg, &As[sn][0], &Bs[sn][0], wave, (long)(tt + 3) * BK);
        compute_step(&As[sl][aoff], &Bs[sl][boff], acc);
        VMCNT(8);
        wg_barrier();
    }
    // Epilogue drain: 8 -> 4 -> 0 outstanding.
    compute_step(&As[tt & 3][aoff], &Bs[tt & 3][boff], acc);
    VMCNT(4);
    wg_barrier();
    ++tt;
    compute_step(&As[tt & 3][aoff], &Bs[tt & 3][boff], acc);
    VMCNT(0);
    wg_barrier();
    ++tt;
    compute_step(&As[tt & 3][aoff], &Bs[tt & 3][boff], acc);

    // Epilogue: C/D layout col = lane&15, row = (lane>>4)*4 + reg  [m89/m91 verified]
    const int crow4 = (lane >> 4) * 4;
    const int ccol = lane & 15;
#pragma unroll
    for (int j = 0; j < 4; j++) {
        const int n = n0 + wn * 64 + j * 16 + ccol;
        const float sc = scale[n];
        const float bi = bias[n];
#pragma unroll
        for (int i = 0; i < 8; i++) {
            const int mbase = m0 + wm * 128 + i * 16 + crow4;
#pragma unroll
            for (int r = 0; r < 4; r++) {
                C[(long)(mbase + r) * N_DIM + n] = acc[i][j][r] * sc + bi;
            }
        }
    }
}

extern "C" void kernel_launch(void* const* d_in, const int* in_sizes, int n_in,
                              void* d_out, int out_size, void* d_ws, size_t ws_size,
                              hipStream_t stream) {
    const float* x = (const float*)d_in[0];       // [M, K] fp32
    const float* w_q = (const float*)d_in[1];     // [N, K] fp32 (fp8-representable)
    const float* scale = (const float*)d_in[2];   // [N]
    const float* bias = (const float*)d_in[3];    // [N]
    float* out = (float*)d_out;                   // [M, N] fp32

    // Workspace layout: x_bf16 (64 MB) | w_bf16 (86 MB)
    __bf16* x_bf = (__bf16*)d_ws;
    __bf16* w_bf = (__bf16*)((char*)d_ws + (size_t)M_DIM * K_DIM * sizeof(__bf16));

    const int n4x = (M_DIM * K_DIM) / 4;
    const int n4w = (N_DIM * K_DIM) / 4;
    cvt_f32_bf16<<<(n4x + 255) / 256, 256, 0, stream>>>(x, (uint2*)x_bf, n4x);
    cvt_f32_bf16<<<(n4w + 255) / 256, 256, 0, stream>>>(w_q, (uint2*)w_bf, n4w);

    gemm_bt_scaled<<<dim3(NBLK), 512, 0, stream>>>(x_bf, w_bf, scale, bias, out);
}

// Round 2
// 1441.474 us; speedup vs baseline: 1.0637x; 1.0637x over previous
//
#include <hip/hip_runtime.h>
#include <hip/hip_bf16.h>
#include <stdint.h>

// Problem constants (QuantizedLinear: B=4,S=2048,D_IN=4096,D_OUT=11008)
#define M_DIM 8192
#define N_DIM 11008
#define K_DIM 4096
#define BM 256
#define BN 256
#define BK 32
#define NT (K_DIM / BK)    // 128 K-steps
#define NBX (N_DIM / BN)   // 43
#define NBY (M_DIM / BM)   // 32
#define NBLK (NBX * NBY)   // 1376 = 8 * 172
#define CPX (NBLK / 8)     // 172 blocks per XCD chunk

typedef __bf16 bf16_8 __attribute__((ext_vector_type(8)));
typedef float f32x4 __attribute__((ext_vector_type(4)));

// ---------------- fp32 -> bf16 (RNE) conversion, 4 elems/thread, fully coalesced ----------------
__device__ __forceinline__ uint32_t pack_bf2(float lo, float hi) {
    uint32_t ulo = __float_as_uint(lo);
    uint32_t uhi = __float_as_uint(hi);
    ulo = (ulo + 0x7fffu + ((ulo >> 16) & 1u)) >> 16;
    uhi = (uhi + 0x7fffu + ((uhi >> 16) & 1u)) >> 16;
    return ulo | (uhi << 16);
}

__global__ __launch_bounds__(256) void cvt_f32_bf16(const float* __restrict__ src,
                                                    uint2* __restrict__ dst, int n4) {
    int i = blockIdx.x * 256 + threadIdx.x;
    if (i >= n4) return;
    float4 a = ((const float4*)src)[i];
    uint2 o;
    o.x = pack_bf2(a.x, a.y);
    o.y = pack_bf2(a.z, a.w);
    dst[i] = o;
}

// ---------------- async global->LDS, 16B per lane ----------------
__device__ __forceinline__ void load_lds16(const __bf16* g, __bf16* l) {
    __builtin_amdgcn_global_load_lds(
        (__attribute__((address_space(1))) void*)(g),
        (__attribute__((address_space(3))) void*)(l),
        16, 0, 0);
}

#define VMCNT(n) asm volatile("s_waitcnt vmcnt(" #n ")" ::: "memory")
#define LGKM0    asm volatile("s_waitcnt lgkmcnt(0)" ::: "memory")
#define SCHED0   __builtin_amdgcn_sched_barrier(0)

__device__ __forceinline__ void wg_barrier() {
    asm volatile("" ::: "memory");
    __builtin_amdgcn_s_barrier();
    asm volatile("" ::: "memory");
}

// Stage one 256-row x 32-k slice (A or W) into an LDS ring slot: 2 wave-loads,
// 16 rows per wave per half. LDS dest lane-linear (global_load_lds requirement);
// k-chunk XOR swizzle applied on the SOURCE address (slot c of LDS row r holds
// global k-chunk c ^ ((r>>1)&3)) -> conflict-free ds_read_b128 on the read side.
__device__ __forceinline__ void stage_pair(const __bf16* G, __bf16* L, int wave, long ko) {
    __bf16* lw = L + wave * 16 * BK;
    load_lds16(G + ko, lw);                                  // rows 0..127 slice
    load_lds16(G + 128L * K_DIM + ko, lw + 128 * BK);        // rows 128..255 slice
}

// ---------------- GEMM: C[m][n] = (A[m][:] . W[n][:]) * scale[n] + bias[n] ----------------
// 256x256 tile, BK=32, 8 waves (2m x 4n), 4-deep LDS ring (128 KiB).
// 8-phase-style schedule (T3+T4+T5): each K-step = 2 phases of
//   {ds_read frags | issue 2 stage loads | barrier | lgkmcnt(0) | 16 MFMA | barrier},
// counted vmcnt(8) once per K-step (3 tiles * 4 loads in flight, never drained
// to 0 in the main loop).
__global__ __launch_bounds__(512, 2) void gemm_bt_scaled(
    const __bf16* __restrict__ A, const __bf16* __restrict__ W,
    const float* __restrict__ scale, const float* __restrict__ bias,
    float* __restrict__ C) {
    __shared__ __align__(16) __bf16 As[4][BM * BK];   // 4 x 16 KiB
    __shared__ __align__(16) __bf16 Bs[4][BN * BK];   // 4 x 16 KiB

    const int t = threadIdx.x;
    const int wave = t >> 6;
    const int lane = t & 63;
    const int wm = wave >> 2;   // 0..1 : wave row (128 rows each)
    const int wn = wave & 3;    // 0..3 : wave col (64 cols each)

    // XCD-aware bijective swizzle: 1376 blocks -> 172-block contiguous chunk per XCD.
    const int bid = (int)blockIdx.x;
    const int swz = (bid & 7) * CPX + (bid >> 3);
    const int by = swz / NBX;
    const int bx = swz - by * NBX;
    const int m0 = by * BM;
    const int n0 = bx * BN;

    // staging source addressing (k-chunk XOR pre-swizzle on global address)
    const int srow = lane >> 2;                            // 0..15
    const int sch = ((lane & 3) ^ ((lane >> 3) & 3)) * 8;  // swizzled k-chunk, elems
    const __bf16* Ag = A + (long)(m0 + wave * 16 + srow) * K_DIM + sch;
    const __bf16* Wg = W + (long)(n0 + wave * 16 + srow) * K_DIM + sch;

    // fragment read addressing (inverse swizzle on the ds_read side)
    const int lrow = lane & 15;
    const int swzr = (lrow >> 1) & 3;
    const int lk = ((lane >> 4) ^ swzr) * 8;
    const int aoff = (wm * 128 + lrow) * BK + lk;
    const int boff = (wn * 64 + lrow) * BK + lk;

    f32x4 acc[8][4] = {};

    // Prologue: stage tiles 0,1,2 (12 loads). vmcnt(8) -> tile 0 landed, 1&2 in flight.
    stage_pair(Ag, &As[0][0], wave, 0);
    stage_pair(Wg, &Bs[0][0], wave, 0);
    stage_pair(Ag, &As[1][0], wave, (long)BK);
    stage_pair(Wg, &Bs[1][0], wave, (long)BK);
    stage_pair(Ag, &As[2][0], wave, 2L * BK);
    stage_pair(Wg, &Bs[2][0], wave, 2L * BK);
    VMCNT(8);
    wg_barrier();

    // Main loop. Slot ledger: stage of tile tt+3 goes to slot (tt+3)&3 = (tt-1)&3,
    // whose readers lgkm-completed before iteration tt-1's final barrier; consumers
    // of tile tt+1 are gated by per-wave VMCNT(8) followed by a barrier.
    int tt = 0;
    for (; tt < NT - 3; ++tt) {
        const int sl = tt & 3;
        const int sn = (tt + 3) & 3;
        const long ko = (long)(tt + 3) * BK;
        const __bf16* Ab = &As[sl][aoff];
        const __bf16* Bb = &Bs[sl][boff];

        // ---- Phase 1: m-frags 0..3 x all n ----
        bf16_8 a0[4], bv[4];
#pragma unroll
        for (int i = 0; i < 4; i++) a0[i] = *(const bf16_8*)(Ab + i * 16 * BK);
#pragma unroll
        for (int j = 0; j < 4; j++) bv[j] = *(const bf16_8*)(Bb + j * 16 * BK);
        stage_pair(Ag, &As[sn][0], wave, ko);
        wg_barrier();
        LGKM0;
        SCHED0;
        __builtin_amdgcn_s_setprio(1);
#pragma unroll
        for (int i = 0; i < 4; i++)
#pragma unroll
            for (int j = 0; j < 4; j++)
                acc[i][j] = __builtin_amdgcn_mfma_f32_16x16x32_bf16(a0[i], bv[j], acc[i][j], 0, 0, 0);
        __builtin_amdgcn_s_setprio(0);
        SCHED0;
        wg_barrier();

        // ---- Phase 2: m-frags 4..7 x all n ----
        bf16_8 a1[4];
#pragma unroll
        for (int i = 0; i < 4; i++) a1[i] = *(const bf16_8*)(Ab + (4 + i) * 16 * BK);
        stage_pair(Wg, &Bs[sn][0], wave, ko);
        wg_barrier();
        LGKM0;
        SCHED0;
        __builtin_amdgcn_s_setprio(1);
#pragma unroll
        for (int i = 0; i < 4; i++)
#pragma unroll
            for (int j = 0; j < 4; j++)
                acc[4 + i][j] = __builtin_amdgcn_mfma_f32_16x16x32_bf16(a1[i], bv[j], acc[4 + i][j], 0, 0, 0);
        __builtin_amdgcn_s_setprio(0);
        SCHED0;
        VMCNT(8);
        wg_barrier();
    }

    // Epilogue drain: 8 -> 4 -> 0 outstanding, then last tile.
#pragma unroll 1
    for (int e = 0; e < 3; ++e) {
        const int sl = (tt + e) & 3;
        const __bf16* Ab = &As[sl][aoff];
        const __bf16* Bb = &Bs[sl][boff];
        bf16_8 af[8], bv[4];
#pragma unroll
        for (int i = 0; i < 8; i++) af[i] = *(const bf16_8*)(Ab + i * 16 * BK);
#pragma unroll
        for (int j = 0; j < 4; j++) bv[j] = *(const bf16_8*)(Bb + j * 16 * BK);
        __builtin_amdgcn_s_setprio(1);
#pragma unroll
        for (int i = 0; i < 8; i++)
#pragma unroll
            for (int j = 0; j < 4; j++)
                acc[i][j] = __builtin_amdgcn_mfma_f32_16x16x32_bf16(af[i], bv[j], acc[i][j], 0, 0, 0);
        __builtin_amdgcn_s_setprio(0);
        if (e == 0) { VMCNT(4); wg_barrier(); }
        else if (e == 1) { VMCNT(0); wg_barrier(); }
    }

    // Epilogue: C/D layout col = lane&15, row = (lane>>4)*4 + reg  [m89/m91 verified]
    const int crow4 = (lane >> 4) * 4;
    const int ccol = lane & 15;
#pragma unroll
    for (int j = 0; j < 4; j++) {
        const int n = n0 + wn * 64 + j * 16 + ccol;
        const float sc = scale[n];
        const float bi = bias[n];
#pragma unroll
        for (int i = 0; i < 8; i++) {
            const int mbase = m0 + wm * 128 + i * 16 + crow4;
#pragma unroll
            for (int r = 0; r < 4; r++) {
                C[(long)(mbase + r) * N_DIM + n] = acc[i][j][r] * sc + bi;
            }
        }
    }
}

extern "C" void kernel_launch(void* const* d_in, const int* in_sizes, int n_in,
                              void* d_out, int out_size, void* d_ws, size_t ws_size,
                              hipStream_t stream) {
    const float* x = (const float*)d_in[0];       // [M, K] fp32
    const float* w_q = (const float*)d_in[1];     // [N, K] fp32 (fp8-representable)
    const float* scale = (const float*)d_in[2];   // [N]
    const float* bias = (const float*)d_in[3];    // [N]
    float* out = (float*)d_out;                   // [M, N] fp32

    // Workspace layout: x_bf16 (64 MB) | w_bf16 (86 MB)
    __bf16* x_bf = (__bf16*)d_ws;
    __bf16* w_bf = (__bf16*)((char*)d_ws + (size_t)M_DIM * K_DIM * sizeof(__bf16));

    const int n4x = (M_DIM * K_DIM) / 4;
    const int n4w = (N_DIM * K_DIM) / 4;
    cvt_f32_bf16<<<(n4x + 255) / 256, 256, 0, stream>>>(x, (uint2*)x_bf, n4x);
    cvt_f32_bf16<<<(n4w + 255) / 256, 256, 0, stream>>>(w_q, (uint2*)w_bf, n4w);

    gemm_bt_scaled<<<dim3(NBLK), 512, 0, stream>>>(x_bf, w_bf, scale, bias, out);
}

// Round 3
// 1417.925 us; speedup vs baseline: 1.0814x; 1.0166x over previous
//
#include <hip/hip_runtime.h>
#include <hip/hip_bf16.h>
#include <stdint.h>

// Problem constants (QuantizedLinear: B=4,S=2048,D_IN=4096,D_OUT=11008)
#define M_DIM 8192
#define N_DIM 11008
#define K_DIM 4096
#define BM 256
#define BN 256
#define BK 32
#define NT (K_DIM / BK)    // 128 K-steps
#define TSLOT (BM * BK)    // elements per A/B ring slot (16 KiB)
#define NBX (N_DIM / BN)   // 43
#define NBY (M_DIM / BM)   // 32
#define NBLK (NBX * NBY)   // 1376 = 8 * 172
#define CPX (NBLK / 8)     // 172 blocks per XCD chunk

typedef __bf16 bf16_8 __attribute__((ext_vector_type(8)));
typedef float f32x4 __attribute__((ext_vector_type(4)));

// ---------------- fp32 -> bf16 (RNE) conversion, 4 elems/thread, fully coalesced ----------------
__device__ __forceinline__ uint32_t pack_bf2(float lo, float hi) {
    uint32_t ulo = __float_as_uint(lo);
    uint32_t uhi = __float_as_uint(hi);
    ulo = (ulo + 0x7fffu + ((ulo >> 16) & 1u)) >> 16;
    uhi = (uhi + 0x7fffu + ((uhi >> 16) & 1u)) >> 16;
    return ulo | (uhi << 16);
}

__global__ __launch_bounds__(256) void cvt_f32_bf16(const float* __restrict__ src,
                                                    uint2* __restrict__ dst, int n4) {
    int i = blockIdx.x * 256 + threadIdx.x;
    if (i >= n4) return;
    float4 a = ((const float4*)src)[i];
    uint2 o;
    o.x = pack_bf2(a.x, a.y);
    o.y = pack_bf2(a.z, a.w);
    dst[i] = o;
}

// ---------------- async global->LDS, 16B per lane ----------------
__device__ __forceinline__ void load_lds16(const __bf16* g, __bf16* l) {
    __builtin_amdgcn_global_load_lds(
        (__attribute__((address_space(1))) void*)(g),
        (__attribute__((address_space(3))) void*)(l),
        16, 0, 0);
}

#define VMCNT(n) asm volatile("s_waitcnt vmcnt(" #n ")" ::: "memory")
#define LGKM(n)  asm volatile("s_waitcnt lgkmcnt(" #n ")" ::: "memory")
#define SCHED0   __builtin_amdgcn_sched_barrier(0)

__device__ __forceinline__ void wg_barrier() {
    asm volatile("" ::: "memory");
    __builtin_amdgcn_s_barrier();
    asm volatile("" ::: "memory");
}

// Stage one 256-row x 32-k slice (A or W) into an LDS ring slot: 2 wave-loads.
// LDS dest lane-linear (global_load_lds requirement); k-chunk XOR swizzle applied
// on the SOURCE address (slot c of LDS row r holds global chunk c ^ ((r>>1)&3)).
__device__ __forceinline__ void stage_pair(const __bf16* G, __bf16* L, int wave, long ko) {
    __bf16* lw = L + wave * 16 * BK;
    load_lds16(G + ko, lw);                                  // rows 0..127 slice
    load_lds16(G + 128L * K_DIM + ko, lw + 128 * BK);        // rows 128..255 slice
}

// One K-step, software-pipelined at register level:
//  ph1: stage A(tt+3) | issue a1 reads | bar | lgkm(4)  (a0,bv ready; a1 in flight)
//       | MFMA a0 x bv (acc rows 0..3)
//  ph2: stage B(tt+3) | issue NEXT step's a0n,bvn reads | lgkm(8) (a1 ready)
//       | MFMA a1 x bv (acc rows 4..7) | vmcnt gate | bar
// Every MFMA cluster overlaps the LDS drain of the next cluster's operands.
template <bool HAS_NEXT>
__device__ __forceinline__ void kstep(
    int tt, const __bf16* AsB, const __bf16* BsB, __bf16* AsW, __bf16* BsW,
    int aoff, int boff, const __bf16* Ag, const __bf16* Wg, int wave,
    bf16_8 (&a0)[4], bf16_8 (&bv)[4],        // current bank (already loaded)
    bf16_8 (&a0n)[4], bf16_8 (&bvn)[4],      // next bank (filled this step)
    bf16_8 (&a1)[4],                         // per-step second A half
    f32x4 (&acc)[8][4]) {
    const int sl = tt & 3;
    const __bf16* Ab = AsB + sl * TSLOT + aoff;
    const __bf16* Bb = BsB + sl * TSLOT + boff;
    const bool doStage = (tt + 3) < NT;
    const int sn = (tt + 3) & 3;
    const long ko = (long)(tt + 3) * BK;

    // ---- phase 1 ----
    if (doStage) stage_pair(Ag, AsW + sn * TSLOT, wave, ko);
#pragma unroll
    for (int i = 0; i < 4; i++) a1[i] = *(const bf16_8*)(Ab + (4 + i) * 16 * BK);
    wg_barrier();            // alignment barrier
    LGKM(4);                 // a0,bv retired; a1's 4 reads still outstanding
    SCHED0;
    __builtin_amdgcn_s_setprio(1);
#pragma unroll
    for (int i = 0; i < 4; i++)
#pragma unroll
        for (int j = 0; j < 4; j++)
            acc[i][j] = __builtin_amdgcn_mfma_f32_16x16x32_bf16(a0[i], bv[j], acc[i][j], 0, 0, 0);
    __builtin_amdgcn_s_setprio(0);

    // ---- phase 2 ----
    if (doStage) stage_pair(Wg, BsW + sn * TSLOT, wave, ko);
    if (HAS_NEXT) {
        const int sl1 = (tt + 1) & 3;
        const __bf16* Abn = AsB + sl1 * TSLOT + aoff;
        const __bf16* Bbn = BsB + sl1 * TSLOT + boff;
#pragma unroll
        for (int i = 0; i < 4; i++) a0n[i] = *(const bf16_8*)(Abn + i * 16 * BK);
#pragma unroll
        for (int j = 0; j < 4; j++) bvn[j] = *(const bf16_8*)(Bbn + j * 16 * BK);
        LGKM(8);             // a1 retired; next-step's 8 reads still outstanding
    } else {
        LGKM(0);             // last step: no prefetch issued, drain a1
    }
    SCHED0;
    __builtin_amdgcn_s_setprio(1);
#pragma unroll
    for (int i = 0; i < 4; i++)
#pragma unroll
        for (int j = 0; j < 4; j++)
            acc[4 + i][j] = __builtin_amdgcn_mfma_f32_16x16x32_bf16(a1[i], bv[j], acc[4 + i][j], 0, 0, 0);
    __builtin_amdgcn_s_setprio(0);

    // vmcnt ledger: at gate, outstanding = tiles tt+2 (4) + tt+3 (4) = 8.
    // Wait-to-4 retires tile tt+2, which step tt+1's ph2 prefetch reads.
    if (tt < NT - 3) { VMCNT(4); }
    else if (tt == NT - 3) { VMCNT(0); }
    wg_barrier();            // ledger barrier: all waves' slices retired
}

// ---------------- GEMM: C[m][n] = (A[m][:] . W[n][:]) * scale[n] + bias[n] ----------------
__global__ __launch_bounds__(512, 2) void gemm_bt_scaled(
    const __bf16* __restrict__ A, const __bf16* __restrict__ W,
    const float* __restrict__ scale, const float* __restrict__ bias,
    float* __restrict__ C) {
    __shared__ __align__(16) __bf16 As[4][TSLOT];   // 4 x 16 KiB ring
    __shared__ __align__(16) __bf16 Bs[4][TSLOT];

    const int t = threadIdx.x;
    const int wave = t >> 6;
    const int lane = t & 63;
    const int wm = wave >> 2;   // 0..1 : wave row (128 rows each)
    const int wn = wave & 3;    // 0..3 : wave col (64 cols each)

    // XCD-aware bijective swizzle: 1376 blocks -> 172-block contiguous chunk per XCD.
    const int bid = (int)blockIdx.x;
    const int swz = (bid & 7) * CPX + (bid >> 3);
    const int by = swz / NBX;
    const int bx = swz - by * NBX;
    const int m0 = by * BM;
    const int n0 = bx * BN;

    // staging source addressing (k-chunk XOR pre-swizzle on global address)
    const int srow = lane >> 2;                            // 0..15
    const int sch = ((lane & 3) ^ ((lane >> 3) & 3)) * 8;  // swizzled k-chunk, elems
    const __bf16* Ag = A + (long)(m0 + wave * 16 + srow) * K_DIM + sch;
    const __bf16* Wg = W + (long)(n0 + wave * 16 + srow) * K_DIM + sch;

    // fragment read addressing (inverse swizzle on the ds_read side)
    const int lrow = lane & 15;
    const int swzr = (lrow >> 1) & 3;
    const int lk = ((lane >> 4) ^ swzr) * 8;
    const int aoff = (wm * 128 + lrow) * BK + lk;
    const int boff = (wn * 64 + lrow) * BK + lk;

    const __bf16* AsB = &As[0][0];
    const __bf16* BsB = &Bs[0][0];
    __bf16* AsW = &As[0][0];
    __bf16* BsW = &Bs[0][0];

    f32x4 acc[8][4] = {};
    bf16_8 a0A[4], bvA[4], a0B[4], bvB[4], a1[4];

    // Prologue: stage tiles 0,1,2; wait tile 0; preload bank A frags for tile 0.
    stage_pair(Ag, AsW + 0 * TSLOT, wave, 0);
    stage_pair(Wg, BsW + 0 * TSLOT, wave, 0);
    stage_pair(Ag, AsW + 1 * TSLOT, wave, (long)BK);
    stage_pair(Wg, BsW + 1 * TSLOT, wave, (long)BK);
    stage_pair(Ag, AsW + 2 * TSLOT, wave, 2L * BK);
    stage_pair(Wg, BsW + 2 * TSLOT, wave, 2L * BK);
    VMCNT(8);               // tile 0 landed (12 outstanding -> 8)
    wg_barrier();
#pragma unroll
    for (int i = 0; i < 4; i++) a0A[i] = *(const bf16_8*)(AsB + aoff + i * 16 * BK);
#pragma unroll
    for (int j = 0; j < 4; j++) bvA[j] = *(const bf16_8*)(BsB + boff + j * 16 * BK);
    // leave the 8 reads in flight: kstep's LGKM(4) is the consumer-side wait

    int tt = 0;
#pragma unroll 1
    for (int it = 0; it < (NT - 2) / 2; ++it) {   // steps 0..NT-3 in parity pairs
        kstep<true>(tt, AsB, BsB, AsW, BsW, aoff, boff, Ag, Wg, wave,
                    a0A, bvA, a0B, bvB, a1, acc);
        ++tt;
        kstep<true>(tt, AsB, BsB, AsW, BsW, aoff, boff, Ag, Wg, wave,
                    a0B, bvB, a0A, bvA, a1, acc);
        ++tt;
    }
    // step NT-2 (even parity, bank A current), then peeled last step NT-1 (bank B)
    kstep<true>(tt, AsB, BsB, AsW, BsW, aoff, boff, Ag, Wg, wave,
                a0A, bvA, a0B, bvB, a1, acc);
    ++tt;
    kstep<false>(tt, AsB, BsB, AsW, BsW, aoff, boff, Ag, Wg, wave,
                 a0B, bvB, a0A, bvA, a1, acc);

    // Epilogue: C/D layout col = lane&15, row = (lane>>4)*4 + reg  [m89/m91 verified]
    const int crow4 = (lane >> 4) * 4;
    const int ccol = lane & 15;
#pragma unroll
    for (int j = 0; j < 4; j++) {
        const int n = n0 + wn * 64 + j * 16 + ccol;
        const float sc = scale[n];
        const float bi = bias[n];
#pragma unroll
        for (int i = 0; i < 8; i++) {
            const int mbase = m0 + wm * 128 + i * 16 + crow4;
#pragma unroll
            for (int r = 0; r < 4; r++) {
                C[(long)(mbase + r) * N_DIM + n] = acc[i][j][r] * sc + bi;
            }
        }
    }
}

extern "C" void kernel_launch(void* const* d_in, const int* in_sizes, int n_in,
                              void* d_out, int out_size, void* d_ws, size_t ws_size,
                              hipStream_t stream) {
    const float* x = (const float*)d_in[0];       // [M, K] fp32
    const float* w_q = (const float*)d_in[1];     // [N, K] fp32 (fp8-representable)
    const float* scale = (const float*)d_in[2];   // [N]
    const float* bias = (const float*)d_in[3];    // [N]
    float* out = (float*)d_out;                   // [M, N] fp32

    // Workspace layout: x_bf16 (64 MB) | w_bf16 (86 MB)
    __bf16* x_bf = (__bf16*)d_ws;
    __bf16* w_bf = (__bf16*)((char*)d_ws + (size_t)M_DIM * K_DIM * sizeof(__bf16));

    const int n4x = (M_DIM * K_DIM) / 4;
    const int n4w = (N_DIM * K_DIM) / 4;
    cvt_f32_bf16<<<(n4x + 255) / 256, 256, 0, stream>>>(x, (uint2*)x_bf, n4x);
    cvt_f32_bf16<<<(n4w + 255) / 256, 256, 0, stream>>>(w_q, (uint2*)w_bf, n4w);

    gemm_bt_scaled<<<dim3(NBLK), 512, 0, stream>>>(x_bf, w_bf, scale, bias, out);
}

// Round 4
// 1339.129 us; speedup vs baseline: 1.1450x; 1.0588x over previous
//
#include <hip/hip_runtime.h>
#include <hip/hip_bf16.h>
#include <stdint.h>

// Problem constants (QuantizedLinear: B=4,S=2048,D_IN=4096,D_OUT=11008)
#define M_DIM 8192
#define N_DIM 11008
#define K_DIM 4096
#define BM 256
#define BN 256
#define BK 32
#define NT (K_DIM / BK)     // 128 K-steps
#define NKS NT              // k-steps in packed-W layout
#define ASLOT (BM * BK)     // elements per A ring slot (16 KiB)
#define NBX (N_DIM / BN)    // 43
#define NBY (M_DIM / BM)    // 32
#define NBLK (NBX * NBY)    // 1376 = 8 * 172
#define CPX (NBLK / 8)      // 172 blocks per XCD chunk

typedef __bf16 bf16_8 __attribute__((ext_vector_type(8)));
typedef float f32x4 __attribute__((ext_vector_type(4)));

// ---------------- fp32 -> bf16 (RNE) packing ----------------
__device__ __forceinline__ uint32_t pack_bf2(float lo, float hi) {
    uint32_t ulo = __float_as_uint(lo);
    uint32_t uhi = __float_as_uint(hi);
    ulo = (ulo + 0x7fffu + ((ulo >> 16) & 1u)) >> 16;
    uhi = (uhi + 0x7fffu + ((uhi >> 16) & 1u)) >> 16;
    return ulo | (uhi << 16);
}

__global__ __launch_bounds__(256) void cvt_f32_bf16(const float* __restrict__ src,
                                                    uint2* __restrict__ dst, int n4) {
    int i = blockIdx.x * 256 + threadIdx.x;
    if (i >= n4) return;
    float4 a = ((const float4*)src)[i];
    uint2 o;
    o.x = pack_bf2(a.x, a.y);
    o.y = pack_bf2(a.z, a.w);
    dst[i] = o;
}

// ---------------- W fp32 [N][K] -> packed fragment-major bf16 ----------------
// Wp frag(jt,ks) = 512 elems (1 KB), lane-linear in the exact 16x16x32 B-operand
// layout: Wp[((jt*NKS+ks)*64 + lane)*8 + e] = bf16(W[jt*16+(lane&15)][ks*32+(lane>>4)*8+e]).
// LDS-transpose so both global read and global write are fully coalesced.
__global__ __launch_bounds__(256) void cvt_w_pack(const float* __restrict__ W,
                                                  __bf16* __restrict__ Wp) {
    __shared__ __bf16 lds[16][136];   // +8 pad: row stride 272 B -> 2-way max (free)
    const int jt = blockIdx.x;        // 0..687 (16-col tile)
    const int kg = blockIdx.y;        // 0..31  (128-k group = 4 k-steps)
    const int tid = threadIdx.x;
    const int r = tid >> 4;           // 0..15 row in tile
    const int c = tid & 15;           // 0..15 8-elem k-chunk
    const float* src = W + (long)(jt * 16 + r) * K_DIM + kg * 128 + c * 8;
    float4 f0 = ((const float4*)src)[0];
    float4 f1 = ((const float4*)src)[1];
    uint4 pk;
    pk.x = pack_bf2(f0.x, f0.y);
    pk.y = pack_bf2(f0.z, f0.w);
    pk.z = pack_bf2(f1.x, f1.y);
    pk.w = pack_bf2(f1.z, f1.w);
    *(uint4*)&lds[r][c * 8] = pk;
    __syncthreads();
    const int ksl = tid >> 6;         // 0..3 local k-step
    const int lane = tid & 63;
    const int rr = lane & 15;
    const int p = lane >> 4;
    uint4 v = *(const uint4*)&lds[rr][ksl * 32 + p * 8];
    ((uint4*)Wp)[(long)((jt * NKS) + kg * 4 + ksl) * 64 + lane] = v;
}

// ---------------- async global->LDS, 16B per lane ----------------
__device__ __forceinline__ void load_lds16(const __bf16* g, __bf16* l) {
    __builtin_amdgcn_global_load_lds(
        (__attribute__((address_space(1))) void*)(g),
        (__attribute__((address_space(3))) void*)(l),
        16, 0, 0);
}

#define VMCNT(n) asm volatile("s_waitcnt vmcnt(" #n ")" ::: "memory")
#define LGKM(n)  asm volatile("s_waitcnt lgkmcnt(" #n ")" ::: "memory")
#define SCHED0   __builtin_amdgcn_sched_barrier(0)

__device__ __forceinline__ void wg_barrier() {
    asm volatile("" ::: "memory");
    __builtin_amdgcn_s_barrier();
    asm volatile("" ::: "memory");
}

// Stage one 256-row x 32-k A slice into an LDS ring slot: 2 wave-loads.
// LDS dest lane-linear (global_load_lds requirement); k-chunk XOR swizzle on the
// SOURCE address (slot c of LDS row r holds global chunk c ^ ((r>>1)&3)).
__device__ __forceinline__ void stage_A(const __bf16* Ag, __bf16* L, int wave, long ko) {
    __bf16* lw = L + wave * 16 * BK;
    load_lds16(Ag + ko, lw);                                  // rows 0..127 slice
    load_lds16(Ag + 128L * K_DIM + ko, lw + 128 * BK);        // rows 128..255 slice
}

// One K-step. B comes straight from packed global (no LDS); A from the LDS ring.
// Per-step ledger (issue order): stage A(t+3) [2 vm] ; B(t+1) [4 vm] ; a1(t) [4 ds]
//   VMCNT(6): retires B(t) + Astage(t+2)   (newest 6 = Astage(t+3)+B(t+1))
//   LGKM(4):  retires a0(t)                (a1(t) still in flight)
//   MFMA a0 x bv ; issue a0(t+1) [4 ds] ; LGKM(4): retires a1(t) ; MFMA a1 x bv
//   barrier (A-ring ledger only)
template <bool STAGE, bool BPRE, bool APRE, int VM>
__device__ __forceinline__ void kstep(
    int tt, const __bf16* AsB, __bf16* AsW, int aoff,
    const __bf16* Ag, int wave, const __bf16* Bp,
    bf16_8 (&a0)[4], bf16_8 (&a0n)[4],
    bf16_8 (&bv)[4], bf16_8 (&bvn)[4],
    bf16_8 (&a1)[4],
    f32x4 (&acc)[8][4]) {
    if (STAGE) {
        stage_A(Ag, AsW + ((tt + 3) & 3) * ASLOT, wave, (long)(tt + 3) * BK);
    }
    if (BPRE) {
#pragma unroll
        for (int j = 0; j < 4; j++)
            bvn[j] = *(const bf16_8*)(Bp + (long)(j * NKS + (tt + 1)) * 512);
    }
    const __bf16* Ab = AsB + (tt & 3) * ASLOT + aoff;
#pragma unroll
    for (int i = 0; i < 4; i++) a1[i] = *(const bf16_8*)(Ab + (4 + i) * 16 * BK);
    if constexpr (VM == 6) VMCNT(6);
    else if constexpr (VM == 4) VMCNT(4);
    else VMCNT(0);
    LGKM(4);
    SCHED0;
    __builtin_amdgcn_s_setprio(1);
#pragma unroll
    for (int i = 0; i < 4; i++)
#pragma unroll
        for (int j = 0; j < 4; j++)
            acc[i][j] = __builtin_amdgcn_mfma_f32_16x16x32_bf16(a0[i], bv[j], acc[i][j], 0, 0, 0);
    __builtin_amdgcn_s_setprio(0);
    if (APRE) {
        const __bf16* Abn = AsB + ((tt + 1) & 3) * ASLOT + aoff;
#pragma unroll
        for (int i = 0; i < 4; i++) a0n[i] = *(const bf16_8*)(Abn + i * 16 * BK);
        LGKM(4);
    } else {
        LGKM(0);
    }
    SCHED0;
    __builtin_amdgcn_s_setprio(1);
#pragma unroll
    for (int i = 0; i < 4; i++)
#pragma unroll
        for (int j = 0; j < 4; j++)
            acc[4 + i][j] = __builtin_amdgcn_mfma_f32_16x16x32_bf16(a1[i], bv[j], acc[4 + i][j], 0, 0, 0);
    __builtin_amdgcn_s_setprio(0);
    if (STAGE || BPRE) wg_barrier();
}

// ---------------- GEMM: C[m][n] = (A[m][:] . W[n][:]) * scale[n] + bias[n] ----------------
__global__ __launch_bounds__(512, 2) void gemm_bt_scaled(
    const __bf16* __restrict__ A, const __bf16* __restrict__ Wp,
    const float* __restrict__ scale, const float* __restrict__ bias,
    float* __restrict__ C) {
    __shared__ __align__(16) __bf16 As[4][ASLOT];   // 64 KiB A ring only

    const int t = threadIdx.x;
    const int wave = t >> 6;
    const int lane = t & 63;
    const int wm = wave >> 2;   // 0..1 : wave row (128 rows each)
    const int wn = wave & 3;    // 0..3 : wave col (64 cols each)

    // XCD-aware bijective swizzle: 1376 blocks -> 172-block contiguous chunk per XCD.
    const int bid = (int)blockIdx.x;
    const int swz = (bid & 7) * CPX + (bid >> 3);
    const int by = swz / NBX;
    const int bx = swz - by * NBX;
    const int m0 = by * BM;
    const int n0 = bx * BN;

    // A staging source addressing (k-chunk XOR pre-swizzle on global address)
    const int srow = lane >> 2;                            // 0..15
    const int sch = ((lane & 3) ^ ((lane >> 3) & 3)) * 8;  // swizzled k-chunk, elems
    const __bf16* Ag = A + (long)(m0 + wave * 16 + srow) * K_DIM + sch;

    // A fragment read addressing (inverse swizzle on the ds_read side)
    const int lrow = lane & 15;
    const int swzr = (lrow >> 1) & 3;
    const int lk = ((lane >> 4) ^ swzr) * 8;
    const int aoff = (wm * 128 + lrow) * BK + lk;

    // packed-B per-wave base: n-tiles jt0..jt0+3, lane-linear frags
    const int jt0 = n0 / 16 + wn * 4;
    const __bf16* Bp = Wp + (long)jt0 * NKS * 512 + lane * 8;

    const __bf16* AsB = &As[0][0];
    __bf16* AsW = &As[0][0];

    f32x4 acc[8][4] = {};
    bf16_8 a0A[4], a0B[4], bvA[4], bvB[4], a1[4];

    // Prologue: stage A tiles 0,1,2 (6 vm); issue B(0) (4 vm).
    stage_A(Ag, AsW + 0 * ASLOT, wave, 0);
    stage_A(Ag, AsW + 1 * ASLOT, wave, (long)BK);
    stage_A(Ag, AsW + 2 * ASLOT, wave, 2L * BK);
#pragma unroll
    for (int j = 0; j < 4; j++)
        bvA[j] = *(const bf16_8*)(Bp + (long)(j * NKS) * 512);
    VMCNT(4);      // newest 4 = B(0) -> ALL A-stages retired; B(0) gated in step 0
    wg_barrier();  // A(0..2) visible to all waves
#pragma unroll
    for (int i = 0; i < 4; i++) a0A[i] = *(const bf16_8*)(AsB + aoff + i * 16 * BK);
    // leave the 4 ds_reads in flight; step 0's LGKM(4) is the consumer-side wait

    int tt = 0;
#pragma unroll 1
    for (int it = 0; it < 62; ++it) {   // steps 0..123 in parity pairs
        kstep<true, true, true, 6>(tt, AsB, AsW, aoff, Ag, wave, Bp,
                                   a0A, a0B, bvA, bvB, a1, acc);
        ++tt;
        kstep<true, true, true, 6>(tt, AsB, AsW, aoff, Ag, wave, Bp,
                                   a0B, a0A, bvB, bvA, a1, acc);
        ++tt;
    }
    // t=124: last staging step (stages A(127)), even parity
    kstep<true, true, true, 6>(tt, AsB, AsW, aoff, Ag, wave, Bp,
                               a0A, a0B, bvA, bvB, a1, acc);
    ++tt;
    // t=125, t=126: no staging; vmcnt ledger shrinks to B-only
    kstep<false, true, true, 4>(tt, AsB, AsW, aoff, Ag, wave, Bp,
                                a0B, a0A, bvB, bvA, a1, acc);
    ++tt;
    kstep<false, true, true, 4>(tt, AsB, AsW, aoff, Ag, wave, Bp,
                                a0A, a0B, bvA, bvB, a1, acc);
    ++tt;
    // t=127: final step, drain everything
    kstep<false, false, false, 0>(tt, AsB, AsW, aoff, Ag, wave, Bp,
                                  a0B, a0A, bvB, bvA, a1, acc);

    // Epilogue: C/D layout col = lane&15, row = (lane>>4)*4 + reg  [m89/m91 verified]
    const int crow4 = (lane >> 4) * 4;
    const int ccol = lane & 15;
#pragma unroll
    for (int j = 0; j < 4; j++) {
        const int n = n0 + wn * 64 + j * 16 + ccol;
        const float sc = scale[n];
        const float bi = bias[n];
#pragma unroll
        for (int i = 0; i < 8; i++) {
            const int mbase = m0 + wm * 128 + i * 16 + crow4;
#pragma unroll
            for (int r = 0; r < 4; r++) {
                C[(long)(mbase + r) * N_DIM + n] = acc[i][j][r] * sc + bi;
            }
        }
    }
}

extern "C" void kernel_launch(void* const* d_in, const int* in_sizes, int n_in,
                              void* d_out, int out_size, void* d_ws, size_t ws_size,
                              hipStream_t stream) {
    const float* x = (const float*)d_in[0];       // [M, K] fp32
    const float* w_q = (const float*)d_in[1];     // [N, K] fp32 (fp8-representable)
    const float* scale = (const float*)d_in[2];   // [N]
    const float* bias = (const float*)d_in[3];    // [N]
    float* out = (float*)d_out;                   // [M, N] fp32

    // Workspace layout: x_bf16 (64 MiB) | Wp packed bf16 (86 MiB)
    __bf16* x_bf = (__bf16*)d_ws;
    __bf16* w_pk = (__bf16*)((char*)d_ws + (size_t)M_DIM * K_DIM * sizeof(__bf16));

    const int n4x = (M_DIM * K_DIM) / 4;
    cvt_f32_bf16<<<(n4x + 255) / 256, 256, 0, stream>>>(x, (uint2*)x_bf, n4x);
    cvt_w_pack<<<dim3(N_DIM / 16, K_DIM / 128), 256, 0, stream>>>(w_q, w_pk);

    gemm_bt_scaled<<<dim3(NBLK), 512, 0, stream>>>(x_bf, w_pk, scale, bias, out);
}